// Round 1
// baseline (16.990 us; speedup 1.0000x reference)
//
#include <hip/hip_runtime.h>

#define S 256
#define HH 512
#define WW 512

__global__ __launch_bounds__(256) void cropface_kernel(
    const float* __restrict__ imgs,
    const float* __restrict__ bboxes,
    const int* __restrict__ has_face,
    float* __restrict__ out,
    int N)
{
#pragma clang fp contract(off)
    int t = blockIdx.x * blockDim.x + threadIdx.x;
    int total = N * S * S;
    if (t >= total) return;
    int n = t >> 16;            // / (256*256)
    int rem = t & 65535;
    int y = rem >> 8;
    int x = rem & 255;

    float* o0 = out + (size_t)(n * 3) * S * S + rem;

    if (has_face[n] != 1) {
        o0[0]       = 0.0f;
        o0[S * S]   = 0.0f;
        o0[2 * S*S] = 0.0f;
        return;
    }

    // ---- compute_bboxes (match numpy op order exactly, no FMA) ----
    float bx0 = bboxes[4 * n + 0], by0 = bboxes[4 * n + 1];
    float bx1 = bboxes[4 * n + 2], by1 = bboxes[4 * n + 3];
    float xmn = fminf(bx0, bx1), xmx = fmaxf(bx0, bx1);
    float ymn = fminf(by0, by1), ymx = fmaxf(by0, by1);
    float cx = (xmn + xmx) * 0.5f;
    float cy = (ymn + ymx) * 0.5f;
    float sxmn = (xmn - cx) * 1.5f; sxmn = sxmn + cx;
    float sxmx = (xmx - cx) * 1.5f; sxmx = sxmx + cx;
    float symn = (ymn - cy) * 1.5f; symn = symn + cy;
    float symx = (ymx - cy) * 1.5f; symx = symx + cy;
    float b0 = fmaxf(sxmn, 0.0f);   // x1
    float b1 = fmaxf(symn, 0.0f);   // y1
    float b2 = fminf(sxmx, 1.0f);   // x2
    float b3 = fminf(symx, 1.0f);   // y2

    int xmin = (int)(b0 * 512.0f);  // trunc == floor (vals >= 0)
    int ymin = (int)(b1 * 512.0f);
    int xmax = (int)(b2 * 512.0f);
    int ymax = (int)(b3 * 512.0f);
    int wci = max(xmax - xmin, 1);
    int hci = max(ymax - ymin, 1);
    float wc = (float)wci, hc = (float)hci;

    // ---- bilinear source coords (exact in fp32, see analysis) ----
    float ys = (float)ymin + ((float)y + 0.5f) * hc / 256.0f - 0.5f;
    ys = fminf(fmaxf(ys, (float)ymin), (float)ymin + hc - 1.0f);
    float xs = (float)xmin + ((float)x + 0.5f) * wc / 256.0f - 0.5f;
    xs = fminf(fmaxf(xs, (float)xmin), (float)xmin + wc - 1.0f);

    int y0 = (int)ys;               // ys >= ymin >= 0 -> trunc == floor
    int x0 = (int)xs;
    int y1i = min(y0 + 1, ymin + hci - 1);
    int x1i = min(x0 + 1, xmin + wci - 1);
    float wy = ys - (float)y0;
    float wx = xs - (float)x0;
    float w00 = (1.0f - wy) * (1.0f - wx);
    float w01 = (1.0f - wy) * wx;
    float w10 = wy * (1.0f - wx);
    float w11 = wy * wx;

    const float* base = imgs + (size_t)n * 3 * HH * WW;
#pragma unroll
    for (int ch = 0; ch < 3; ++ch) {
        const float* p = base + (size_t)ch * HH * WW;
        float g00 = p[y0  * WW + x0 ];
        float g01 = p[y0  * WW + x1i];
        float g10 = p[y1i * WW + x0 ];
        float g11 = p[y1i * WW + x1i];
        float acc = w00 * g00;
        acc = acc + w01 * g01;
        acc = acc + w10 * g10;
        acc = acc + w11 * g11;
        o0[ch * S * S] = acc;
    }
}

extern "C" void kernel_launch(void* const* d_in, const int* in_sizes, int n_in,
                              void* d_out, int out_size, void* d_ws, size_t ws_size,
                              hipStream_t stream) {
    const float* imgs     = (const float*)d_in[0];
    const float* bboxes   = (const float*)d_in[1];
    const int*   has_face = (const int*)d_in[2];
    float* out = (float*)d_out;
    int N = in_sizes[2];                 // 32 images
    int total = N * S * S;               // one thread per output pixel (3 ch each)
    int block = 256;
    int grid = (total + block - 1) / block;
    cropface_kernel<<<grid, block, 0, stream>>>(imgs, bboxes, has_face, out, N);
}